// Round 6
// baseline (457.441 us; speedup 1.0000x reference)
//
#include <hip/hip_runtime.h>
#include <math.h>

namespace {

constexpr int C_ = 3, T_ = 3000, F_ = 103, NB_ = 6;
constexpr int TT = 20;                        // 3000/20 = 150 blocks along T
constexpr int BS_[NB_]  = {1, 10, 20, 30, 40, 61};
constexpr int BNB_[NB_] = {10, 11, 11, 11, 22, 16};
constexpr int BP_[NB_]  = {12, 12, 12, 12, 24, 16};   // padded to x4
constexpr int BPS_[NB_] = {0, 12, 24, 36, 48, 72};    // cumsum BP, total 88
constexpr int WOFP_[NB_] = {0, 216, 432, 648, 864, 1296}; // cumsum 18*BP
constexpr int WTOTP = 1584;                   // padded gaussian weights (floats)
constexpr int SLOTS = 88;                     // band-sliced cols per (c,tt)
constexpr int CTSTR = 92;                     // padded row stride
constexpr int SPECN = C_ * TT * CTSTR;        // 5520
constexpr int PLANE = T_ * F_;                // 309000
constexpr int SEC  = TT * F_;                 // 2060 (%4==0)
constexpr int SECP = 2064;                    // enh plane stride (x4)
constexpr int POOLN = SPECN + WTOTP;          // 7104 >= 3*SECP=6192 (aliased by enh)

__device__ __forceinline__ float softplus_full_(float x) {
  return fmaxf(x, 0.0f) + log1pf(expf(-fabsf(x)));
}
__device__ __forceinline__ float sigmoid_(float z) {
  return 1.0f / (1.0f + __expf(-z));
}
__device__ __forceinline__ float gelu_(float x) {
  return x * sigmoid_(1.595769122f * x * (1.0f + 0.044715f * x * x));
}

// ---- pre-kernel: padded gaussian bank + folded proj/BN -> d_ws ----------------
// d_ws floats: [0..1583] padded weights, [1584..1592] projBN w, [1593..1595] projBN b
__global__ __launch_bounds__(128)
void prep_kernel(const float* __restrict__ centers,
                 const float* __restrict__ widths,
                 const float* __restrict__ gains,
                 const float* __restrict__ proj_w,
                 const float* __restrict__ proj_b,
                 const float* __restrict__ bn_gamma,
                 const float* __restrict__ bn_beta,
                 const float* __restrict__ bn_mean,
                 const float* __restrict__ bn_var,
                 float* __restrict__ ws)
{
  const int q = threadIdx.x;
  if (q < 108) {
    int i = q / 18;
    int p = q - i * 18;
    int s = BS_[i], nb = BNB_[i];
    float mu = softplus_full_(centers[q]) + (float)s;
    mu = fminf(fmaxf(mu, (float)s), (float)(s + nb - 1));
    float sd = softplus_full_(widths[q]) + 0.001f;
    sd = fminf(fmaxf(sd, 0.5f), 2.0f * (float)nb / 6.0f);
    float sum = 0.0f;
    for (int f = 0; f < nb; ++f) {
      float d = ((float)f - mu) / sd;
      sum += __expf(-0.5f * d * d);
    }
    float sc = gains[q] / (sum + 1e-6f);
    float* wrow = &ws[WOFP_[i] + p * BP_[i]];
    for (int f = 0; f < nb; ++f) {
      float d = ((float)f - mu) / sd;
      wrow[f] = sc * __expf(-0.5f * d * d);
    }
    for (int f = nb; f < BP_[i]; ++f) wrow[f] = 0.0f;   // zero pads
  } else if (q < 117) {
    int k = q - 108, d = k / 3;
    float sc = bn_gamma[d] / sqrtf(bn_var[d] + 1e-5f);
    ws[WTOTP + k] = proj_w[k] * sc;
  } else if (q < 120) {
    int d = q - 117;
    float sc = bn_gamma[d] / sqrtf(bn_var[d] + 1e-5f);
    ws[WTOTP + 9 + d] = (proj_b[d] - bn_mean[d]) * sc + bn_beta[d];
  }
}

// ---- main kernel --------------------------------------------------------------
__global__ __launch_bounds__(256)
void sleepband_kernel(const float* __restrict__ spec,
                      const float* __restrict__ ws,
                      const float* __restrict__ align_w,
                      const float* __restrict__ align_b,
                      const float* __restrict__ fc1_w,
                      const float* __restrict__ fc1_b,
                      const float* __restrict__ fc2_w,
                      const float* __restrict__ fc2_b,
                      const float* __restrict__ band_gain,
                      const float* __restrict__ gate_w,
                      const float* __restrict__ gate_b,
                      float* __restrict__ out)
{
  // pool: [stage/A] sSpecB[60][92] (5520) + sWB (1584)  ||  [B2/final] enh[3][SECP]
  __shared__ __align__(16) float sPool[POOLN];
  __shared__ float sBand[TT][109];   // odd stride -> conflict-free
  __shared__ float sAw[54], sAb[18], sF1[108], sF1b[6], sF2[108], sF2b[18],
                   sBg[6], sGw[9], sGb[3], sPw[9], sPb[3];

  const int tid = threadIdx.x;
  const int t0  = blockIdx.x * TT;
  const int b   = blockIdx.y;
  const float* specB = spec + (size_t)b * C_ * PLANE;

  // ---- stage spec, band-sliced + padded ----
  for (int li = tid; li < C_ * TT * SLOTS; li += 256) {
    int ctt  = li / SLOTS;
    int slot = li - ctt * SLOTS;
    int c    = ctt / TT;
    int tt   = ctt - c * TT;
    int i    = (slot >= 72) ? 5 : ((slot >= 48) ? 4 : (slot / 12));
    int j    = slot - BPS_[i];
    float v  = 0.0f;
    if (j < BNB_[i])
      v = specB[(size_t)c * PLANE + (size_t)(t0 + tt) * F_ + (BS_[i] + j)];
    sPool[ctt * CTSTR + slot] = v;
  }
  // stage padded gaussian weights (L2-hot)
  for (int k = tid; k < WTOTP; k += 256) sPool[SPECN + k] = ws[k];

  // ---- stage small params into LDS (once; hot phases never touch global) ----
  if (tid < 54)  sAw[tid]  = align_w[tid];
  if (tid < 18)  sAb[tid]  = align_b[tid];
  if (tid < 108) sF1[tid]  = fc1_w[tid];
  if (tid < 6)   sF1b[tid] = fc1_b[tid];
  if (tid < 108) sF2[tid]  = fc2_w[tid];
  if (tid < 18)  sF2b[tid] = fc2_b[tid];
  if (tid < 6)   sBg[tid]  = band_gain[tid];
  if (tid < 9)   sGw[tid]  = gate_w[tid];
  if (tid < 3)   sGb[tid]  = gate_b[tid];
  if (tid < 9)   sPw[tid]  = ws[WTOTP + tid];
  if (tid < 3)   sPb[tid]  = ws[WTOTP + 9 + tid];
  __syncthreads();

  // ---- Phase A: filt via float4 MAC (360 tasks) ----
  for (int task = tid; task < 18 * TT; task += 256) {
    const int p  = task / TT;
    const int tt = task - p * TT;
    const int c  = p / 6;
    const int n  = p - c * 6;
    const float* srow = &sPool[(c * TT + tt) * CTSTR];
    const float* wall = &sPool[SPECN];
    #pragma unroll
    for (int i = 0; i < NB_; ++i) {
      const float4* s4 = (const float4*)(srow + BPS_[i]);
      const float4* w4 = (const float4*)(wall + WOFP_[i] + p * BP_[i]);
      float4 a = {0.0f, 0.0f, 0.0f, 0.0f};
      #pragma unroll
      for (int k = 0; k < BP_[i] / 4; ++k) {
        float4 sv = s4[k], wv = w4[k];
        a.x += sv.x * wv.x; a.y += sv.y * wv.y;
        a.z += sv.z * wv.z; a.w += sv.w * wv.w;
      }
      sBand[tt][(i * 3 + c) * 6 + n] = (a.x + a.y) + (a.z + a.w);
    }
  }
  __syncthreads();

  // ---- Phase B: align + MLP + softmax + scale (120 tasks) ----
  if (tid < 6 * TT) {
    const int n  = tid / TT;
    const int tt = tid - n * TT;
    float al[18];
    #pragma unroll
    for (int i = 0; i < 6; ++i) {
      float f0 = sBand[tt][(i * 3 + 0) * 6 + n];
      float f1 = sBand[tt][(i * 3 + 1) * 6 + n];
      float f2 = sBand[tt][(i * 3 + 2) * 6 + n];
      #pragma unroll
      for (int d = 0; d < 3; ++d)
        al[i * 3 + d] = sAw[i * 9 + d * 3 + 0] * f0 + sAw[i * 9 + d * 3 + 1] * f1 +
                        sAw[i * 9 + d * 3 + 2] * f2 + sAb[i * 3 + d];
    }
    float h[6];
    #pragma unroll
    for (int o = 0; o < 6; ++o) {
      float acc = sF1b[o];
      #pragma unroll
      for (int k = 0; k < 18; ++k) acc += sF1[o * 18 + k] * al[k];
      h[o] = gelu_(acc);
    }
    float at[18];
    #pragma unroll
    for (int k = 0; k < 18; ++k) {
      float acc = sF2b[k];
      #pragma unroll
      for (int o = 0; o < 6; ++o) acc += sF2[k * 6 + o] * h[o];
      at[k] = acc;
    }
    #pragma unroll
    for (int c = 0; c < 3; ++c) {
      float m = at[c];
      #pragma unroll
      for (int i = 1; i < 6; ++i) m = fmaxf(m, at[i * 3 + c]);
      float e[6], ssum = 0.0f;
      #pragma unroll
      for (int i = 0; i < 6; ++i) { e[i] = __expf(at[i * 3 + c] - m); ssum += e[i]; }
      float inv = 1.0f / ssum;
      #pragma unroll
      for (int i = 0; i < 6; ++i)
        sBand[tt][(i * 3 + c) * 6 + n] = al[i * 3 + c] * (e[i] * inv) * sBg[i];
    }
  }
  __syncthreads();

  // ---- Phase B2: compile-time-tap upsample into dense enh (60 tasks) ----
  if (tid < C_ * TT) {
    const int c  = tid / TT;
    const int tt = tid - c * TT;
    float bnd[36];
    #pragma unroll
    for (int i = 0; i < 6; ++i)
      #pragma unroll
      for (int n = 0; n < 6; ++n)
        bnd[i * 6 + n] = sBand[tt][(i * 3 + c) * 6 + n];
    float* row = &sPool[c * SECP + tt * F_];
    row[0] = 0.0f;
    float carry = 0.0f;
    #pragma unroll
    for (int i = 0; i < NB_; ++i) {
      #pragma unroll
      for (int j = 0; j < BNB_[i]; ++j) {
        float src = ((float)j + 0.5f) * 6.0f / (float)BNB_[i] - 0.5f;
        src = src > 0.0f ? src : 0.0f;
        int   x0 = (int)src;
        int   x1 = (x0 < 5) ? x0 + 1 : 5;
        float wl = src - (float)x0;
        float v  = bnd[i * 6 + x0] * (1.0f - wl) + bnd[i * 6 + x1] * wl;
        if (j == 0) v += carry;
        if (i < NB_ - 1 && j == BNB_[i] - 1) carry = v;
        else row[BS_[i] + j] = v;
      }
    }
    #pragma unroll
    for (int f = 77; f < F_; ++f) row[f] = 0.0f;
  }
  __syncthreads();

  // ---- Final: flat float4 gate + folded proj + gelu ----
  float gw[9], pw[9], gb3[3], pb3[3];
  #pragma unroll
  for (int k = 0; k < 9; ++k) { gw[k] = sGw[k]; pw[k] = sPw[k]; }
  #pragma unroll
  for (int k = 0; k < 3; ++k) { gb3[k] = sGb[k]; pb3[k] = sPb[k]; }

  const float* sp0 = specB + (size_t)t0 * F_;
  float* outB = out + (size_t)b * C_ * PLANE + (size_t)t0 * F_;
  for (int e4 = tid; e4 < SEC / 4; e4 += 256) {
    const int e = e4 * 4;
    const float4 sA = *(const float4*)(sp0 + e);
    const float4 sB = *(const float4*)(sp0 + PLANE + e);
    const float4 sC = *(const float4*)(sp0 + 2 * PLANE + e);
    const float4 eA = *(const float4*)&sPool[0 * SECP + e];
    const float4 eB = *(const float4*)&sPool[1 * SECP + e];
    const float4 eC = *(const float4*)&sPool[2 * SECP + e];
    float4 oA, oB, oC;
    const float* sAp = (const float*)&sA; const float* sBp = (const float*)&sB;
    const float* sCp = (const float*)&sC;
    const float* eAp = (const float*)&eA; const float* eBp = (const float*)&eB;
    const float* eCp = (const float*)&eC;
    float* oAp = (float*)&oA; float* oBp = (float*)&oB; float* oCp = (float*)&oC;
    #pragma unroll
    for (int j = 0; j < 4; ++j) {
      float sv0 = sAp[j], sv1 = sBp[j], sv2 = sCp[j];
      float r0 = eAp[j] - sv0, r1 = eBp[j] - sv1, r2 = eCp[j] - sv2;
      float e20 = sv0 + sigmoid_(gw[0] * r0 + gw[1] * r1 + gw[2] * r2 + gb3[0]) * r0;
      float e21 = sv1 + sigmoid_(gw[3] * r0 + gw[4] * r1 + gw[5] * r2 + gb3[1]) * r1;
      float e22 = sv2 + sigmoid_(gw[6] * r0 + gw[7] * r1 + gw[8] * r2 + gb3[2]) * r2;
      float y0 = pw[0] * e20 + pw[1] * e21 + pw[2] * e22 + pb3[0];
      float y1 = pw[3] * e20 + pw[4] * e21 + pw[5] * e22 + pb3[1];
      float y2 = pw[6] * e20 + pw[7] * e21 + pw[8] * e22 + pb3[2];
      oAp[j] = gelu_(y0); oBp[j] = gelu_(y1); oCp[j] = gelu_(y2);
    }
    *(float4*)(outB + e) = oA;
    *(float4*)(outB + PLANE + e) = oB;
    *(float4*)(outB + 2 * PLANE + e) = oC;
  }
}

} // namespace

extern "C" void kernel_launch(void* const* d_in, const int* in_sizes, int n_in,
                              void* d_out, int out_size, void* d_ws, size_t ws_size,
                              hipStream_t stream) {
  (void)n_in; (void)out_size; (void)ws_size;
  const int B = in_sizes[0] / (C_ * T_ * F_);   // 64
  float* ws = (float*)d_ws;                     // 1596 floats used
  prep_kernel<<<1, 128, 0, stream>>>(
      (const float*)d_in[1],  (const float*)d_in[2],  (const float*)d_in[3],
      (const float*)d_in[13], (const float*)d_in[14], (const float*)d_in[15],
      (const float*)d_in[16], (const float*)d_in[17], (const float*)d_in[18], ws);
  dim3 grid(T_ / TT, B);                        // (150, 64)
  sleepband_kernel<<<grid, 256, 0, stream>>>(
      (const float*)d_in[0],  ws,
      (const float*)d_in[4],  (const float*)d_in[5],
      (const float*)d_in[6],  (const float*)d_in[7],  (const float*)d_in[8],
      (const float*)d_in[9],  (const float*)d_in[10], (const float*)d_in[11],
      (const float*)d_in[12], (float*)d_out);
}

// Round 7
// 254.457 us; speedup vs baseline: 1.7977x; 1.7977x over previous
//
#include <hip/hip_runtime.h>
#include <math.h>

namespace {

constexpr int C_ = 3, T_ = 3000, F_ = 103, NB_ = 6;
constexpr int TT = 20;                       // 3000/20=150; TT*F=2060 %4==0
constexpr int BS[NB_]  = {1, 10, 20, 30, 40, 61};
constexpr int BNB[NB_] = {10, 11, 11, 11, 22, 16};
constexpr int BOF[NB_] = {0, 10, 21, 32, 43, 65};   // cumsum, total 81
constexpr int SPF = 81;                      // staged spec cols (bands span f=1..76)
constexpr int PLANE = T_ * F_;               // 309000
constexpr int SECP = 2064;                   // enh plane stride (2060 padded to x4)
constexpr int POOLN = 6320;                  // max(4860+1458, 3*2064)=6318 -> 6320

__device__ __forceinline__ float softplus_(float x) {
  return fmaxf(x, 0.0f) + log1pf(expf(-fabsf(x)));
}
__device__ __forceinline__ float sigmoid_(float z) {
  return 1.0f / (1.0f + __expf(-z));
}
__device__ __forceinline__ float gelu_(float x) {
  return x * sigmoid_(1.595769122f * x * (1.0f + 0.044715f * x * x));
}

__global__ __launch_bounds__(256)
void sleepband_kernel(const float* __restrict__ spec,
                      const float* __restrict__ centers,
                      const float* __restrict__ widths,
                      const float* __restrict__ gains,
                      const float* __restrict__ align_w,
                      const float* __restrict__ align_b,
                      const float* __restrict__ fc1_w,
                      const float* __restrict__ fc1_b,
                      const float* __restrict__ fc2_w,
                      const float* __restrict__ fc2_b,
                      const float* __restrict__ band_gain,
                      const float* __restrict__ gate_w,
                      const float* __restrict__ gate_b,
                      const float* __restrict__ proj_w,
                      const float* __restrict__ proj_b,
                      const float* __restrict__ bn_gamma,
                      const float* __restrict__ bn_beta,
                      const float* __restrict__ bn_mean,
                      const float* __restrict__ bn_var,
                      float* __restrict__ out)
{
  // Pool: [Phase A] sSpec[C][TT][81] (4860) + sW (1458)  ||  [B2/final] sEnh[3][SECP]
  __shared__ __align__(16) float sPool[POOLN];
  __shared__ float sBand[TT][109];       // 108 used, pad 109 (odd stride) -> conflict-free
  __shared__ float sAw[54], sAb[18], sF1[108], sF1b[6], sF2[108], sF2b[18],
                   sBg[6], sGw[9], sGb[3], sPw[9], sPb[3];

  const int tid = threadIdx.x;
  const int t0  = blockIdx.x * TT;
  const int b   = blockIdx.y;

  float* sW = sPool + C_ * TT * SPF;     // gaussian weights, Phase A only

  // ---------------- stage spec band region (coalesced) ----------------
  const float* specB = spec + (size_t)b * C_ * PLANE;
  for (int li = tid; li < C_ * TT * SPF; li += 256) {
    int c   = li / (TT * SPF);
    int rem = li - c * (TT * SPF);
    int tt  = rem / SPF;
    int f   = rem - tt * SPF;
    sPool[li] = specB[(size_t)c * PLANE + (size_t)(t0 + tt) * F_ + f];
  }

  // ---------------- prefetch final-phase spec reads into registers ----------
  // These drain at barrier 1 (which waits vmcnt(0) for staging regardless), so
  // the final phase runs with zero global-load latency.
  const float* sp0 = specB + (size_t)t0 * F_;
  const int e1 = tid * 4;
  const int e2 = e1 + 1024;                  // (tid+256)*4, max 2044+3 < 2060
  const float4 pA1 = *(const float4*)(sp0 + e1);
  const float4 pB1 = *(const float4*)(sp0 + PLANE + e1);
  const float4 pC1 = *(const float4*)(sp0 + 2 * PLANE + e1);
  const float4 pA2 = *(const float4*)(sp0 + e2);
  const float4 pB2 = *(const float4*)(sp0 + PLANE + e2);
  const float4 pC2 = *(const float4*)(sp0 + 2 * PLANE + e2);
  float4 pA3 = {0,0,0,0}, pB3 = {0,0,0,0}, pC3 = {0,0,0,0};
  const int e3 = 2048 + tid * 4;             // tail: e4 = 512..514
  if (tid < 3) {
    pA3 = *(const float4*)(sp0 + e3);
    pB3 = *(const float4*)(sp0 + PLANE + e3);
    pC3 = *(const float4*)(sp0 + 2 * PLANE + e3);
  }

  // ---------------- stage small params ----------------
  if (tid < 54)  sAw[tid]  = align_w[tid];
  if (tid < 18)  sAb[tid]  = align_b[tid];
  if (tid < 108) sF1[tid]  = fc1_w[tid];
  if (tid < 6)   sF1b[tid] = fc1_b[tid];
  if (tid < 108) sF2[tid]  = fc2_w[tid];
  if (tid < 18)  sF2b[tid] = fc2_b[tid];
  if (tid < 6)   sBg[tid]  = band_gain[tid];
  if (tid < 9)   sGw[tid]  = gate_w[tid];
  if (tid < 3)   sGb[tid]  = gate_b[tid];
  if (tid < 9) {                          // proj folded with BN scale
    int d = tid / 3;
    float sc = bn_gamma[d] / sqrtf(bn_var[d] + 1e-5f);
    sPw[tid] = proj_w[tid] * sc;
  }
  if (tid < 3) {                          // bias folded with BN offset
    float sc = bn_gamma[tid] / sqrtf(bn_var[tid] + 1e-5f);
    sPb[tid] = (proj_b[tid] - bn_mean[tid]) * sc + bn_beta[tid];
  }

  // ---------------- gaussian filter bank (108 tasks, waves 2-3) ----------------
  if (tid >= 128 && tid < 128 + 108) {
    int q = tid - 128;
    int i = q / 18;                       // band
    int p = q - i * 18;                   // c*6+n ; flat centers idx == q
    int s = BS[i], nb = BNB[i];
    float mu = softplus_(centers[q]) + (float)s;
    mu = fminf(fmaxf(mu, (float)s), (float)(s + nb - 1));
    float sd = softplus_(widths[q]) + 0.001f;
    sd = fminf(fmaxf(sd, 0.5f), 2.0f * (float)nb / 6.0f);
    float sum = 0.0f;
    for (int f = 0; f < nb; ++f) {
      float d = ((float)f - mu) / sd;
      sum += __expf(-0.5f * d * d);
    }
    float sc = gains[q] / (sum + 1e-6f);
    float* wrow = &sW[BOF[i] * 18 + p * nb];
    for (int f = 0; f < nb; ++f) {
      float d = ((float)f - mu) / sd;
      wrow[f] = sc * __expf(-0.5f * d * d);
    }
  }
  __syncthreads();

  // ---------------- Phase A: filt (18*TT=360 tasks) ----------------
  for (int task = tid; task < 18 * TT; task += 256) {
    int p  = task / TT;
    int tt = task - p * TT;
    int c  = p / 6;
    int n  = p - c * 6;
    const float* srowb = &sPool[(c * TT + tt) * SPF];
    #pragma unroll
    for (int i = 0; i < NB_; ++i) {
      const float* wrow = &sW[BOF[i] * 18 + p * BNB[i]];
      const float* srow = srowb + BS[i];
      float acc = 0.0f;
      #pragma unroll
      for (int f = 0; f < BNB[i]; ++f) acc += srow[f] * wrow[f];
      sBand[tt][(i * 3 + c) * 6 + n] = acc;
    }
  }
  __syncthreads();

  // ---------------- Phase B: align + attention + softmax + scale (6*TT tasks) ----
  if (tid < 6 * TT) {
    int n  = tid / TT;
    int tt = tid - n * TT;
    float al[18];
    #pragma unroll
    for (int i = 0; i < 6; ++i) {
      float f0 = sBand[tt][(i * 3 + 0) * 6 + n];
      float f1 = sBand[tt][(i * 3 + 1) * 6 + n];
      float f2 = sBand[tt][(i * 3 + 2) * 6 + n];
      #pragma unroll
      for (int d = 0; d < 3; ++d)
        al[i * 3 + d] = sAw[i * 9 + d * 3 + 0] * f0 + sAw[i * 9 + d * 3 + 1] * f1 +
                        sAw[i * 9 + d * 3 + 2] * f2 + sAb[i * 3 + d];
    }
    float h[6];
    #pragma unroll
    for (int o = 0; o < 6; ++o) {
      float acc = sF1b[o];
      #pragma unroll
      for (int k = 0; k < 18; ++k) acc += sF1[o * 18 + k] * al[k];
      h[o] = gelu_(acc);
    }
    float at[18];
    #pragma unroll
    for (int k = 0; k < 18; ++k) {
      float acc = sF2b[k];
      #pragma unroll
      for (int o = 0; o < 6; ++o) acc += sF2[k * 6 + o] * h[o];
      at[k] = acc;
    }
    #pragma unroll
    for (int c = 0; c < 3; ++c) {
      float m = at[c];
      #pragma unroll
      for (int i = 1; i < 6; ++i) m = fmaxf(m, at[i * 3 + c]);
      float e[6], ssum = 0.0f;
      #pragma unroll
      for (int i = 0; i < 6; ++i) { e[i] = __expf(at[i * 3 + c] - m); ssum += e[i]; }
      float inv = 1.0f / ssum;
      #pragma unroll
      for (int i = 0; i < 6; ++i)
        sBand[tt][(i * 3 + c) * 6 + n] = al[i * 3 + c] * (e[i] * inv) * sBg[i];
    }
  }
  __syncthreads();

  // ---------------- Phase B2: compile-time-tap upsample into dense enh ----------
  if (tid < C_ * TT) {
    const int c  = tid / TT;
    const int tt = tid - c * TT;
    float bnd[36];
    #pragma unroll
    for (int i = 0; i < 6; ++i)
      #pragma unroll
      for (int n = 0; n < 6; ++n)
        bnd[i * 6 + n] = sBand[tt][(i * 3 + c) * 6 + n];
    float* row = &sPool[c * SECP + tt * F_];
    row[0] = 0.0f;
    float carry = 0.0f;
    #pragma unroll
    for (int i = 0; i < NB_; ++i) {
      #pragma unroll
      for (int j = 0; j < BNB[i]; ++j) {
        float src = ((float)j + 0.5f) * 6.0f / (float)BNB[i] - 0.5f;
        src = src > 0.0f ? src : 0.0f;
        int   x0 = (int)src;
        int   x1 = (x0 < 5) ? x0 + 1 : 5;
        float wl = src - (float)x0;
        float v  = bnd[i * 6 + x0] * (1.0f - wl) + bnd[i * 6 + x1] * wl;
        if (j == 0) v += carry;
        if (i < NB_ - 1 && j == BNB[i] - 1) carry = v;
        else row[BS[i] + j] = v;
      }
    }
    #pragma unroll
    for (int f = 77; f < F_; ++f) row[f] = 0.0f;
  }
  __syncthreads();

  // ---------------- Final: gate + folded proj + gelu (prefetched spec) ----------
  float gw[9], pw[9], gb3[3], pb3[3];
  #pragma unroll
  for (int k = 0; k < 9; ++k) { gw[k] = sGw[k]; pw[k] = sPw[k]; }
  #pragma unroll
  for (int k = 0; k < 3; ++k) { gb3[k] = sGb[k]; pb3[k] = sPb[k]; }

  float* outB = out + (size_t)b * C_ * PLANE + (size_t)t0 * F_;

  auto fin = [&](int e, const float4& sA, const float4& sB, const float4& sC) {
    const float4 eA = *(const float4*)&sPool[0 * SECP + e];
    const float4 eB = *(const float4*)&sPool[1 * SECP + e];
    const float4 eC = *(const float4*)&sPool[2 * SECP + e];
    float4 oA, oB, oC;
    const float* sAp = (const float*)&sA; const float* sBp = (const float*)&sB;
    const float* sCp = (const float*)&sC;
    const float* eAp = (const float*)&eA; const float* eBp = (const float*)&eB;
    const float* eCp = (const float*)&eC;
    float* oAp = (float*)&oA; float* oBp = (float*)&oB; float* oCp = (float*)&oC;
    #pragma unroll
    for (int j = 0; j < 4; ++j) {
      float sv0 = sAp[j], sv1 = sBp[j], sv2 = sCp[j];
      float r0 = eAp[j] - sv0, r1 = eBp[j] - sv1, r2 = eCp[j] - sv2;
      float e20 = sv0 + sigmoid_(gw[0] * r0 + gw[1] * r1 + gw[2] * r2 + gb3[0]) * r0;
      float e21 = sv1 + sigmoid_(gw[3] * r0 + gw[4] * r1 + gw[5] * r2 + gb3[1]) * r1;
      float e22 = sv2 + sigmoid_(gw[6] * r0 + gw[7] * r1 + gw[8] * r2 + gb3[2]) * r2;
      float y0 = pw[0] * e20 + pw[1] * e21 + pw[2] * e22 + pb3[0];
      float y1 = pw[3] * e20 + pw[4] * e21 + pw[5] * e22 + pb3[1];
      float y2 = pw[6] * e20 + pw[7] * e21 + pw[8] * e22 + pb3[2];
      oAp[j] = gelu_(y0); oBp[j] = gelu_(y1); oCp[j] = gelu_(y2);
    }
    *(float4*)(outB + e) = oA;
    *(float4*)(outB + PLANE + e) = oB;
    *(float4*)(outB + 2 * PLANE + e) = oC;
  };

  fin(e1, pA1, pB1, pC1);
  fin(e2, pA2, pB2, pC2);
  if (tid < 3) fin(e3, pA3, pB3, pC3);
}

} // namespace

extern "C" void kernel_launch(void* const* d_in, const int* in_sizes, int n_in,
                              void* d_out, int out_size, void* d_ws, size_t ws_size,
                              hipStream_t stream) {
  (void)n_in; (void)out_size; (void)d_ws; (void)ws_size;
  const int B = in_sizes[0] / (C_ * T_ * F_);   // 64
  dim3 grid(T_ / TT, B);                        // (150, 64)
  sleepband_kernel<<<grid, 256, 0, stream>>>(
      (const float*)d_in[0],  (const float*)d_in[1],  (const float*)d_in[2],
      (const float*)d_in[3],  (const float*)d_in[4],  (const float*)d_in[5],
      (const float*)d_in[6],  (const float*)d_in[7],  (const float*)d_in[8],
      (const float*)d_in[9],  (const float*)d_in[10], (const float*)d_in[11],
      (const float*)d_in[12], (const float*)d_in[13], (const float*)d_in[14],
      (const float*)d_in[15], (const float*)d_in[16], (const float*)d_in[17],
      (const float*)d_in[18], (float*)d_out);
}